// Round 13
// baseline (89.418 us; speedup 1.0000x reference)
//
#include <hip/hip_runtime.h>
#include <math.h>

typedef short  short8 __attribute__((ext_vector_type(8)));
typedef float  f32x4  __attribute__((ext_vector_type(4)));

#define ZQ_ELEMS 4194304    // 16*64*64*64
#define KC       1024
#define EPS_HALF 0.005f

// Output layout (fp32, concat): [0,4194304) z_q_st ; [4194304] vq_loss ;
// [4194305, 4259841) indices (as float)
//
// ws layout (bytes):
//   [0,262144)        ushort epack[1024][128]   per code: hi[64] | lo[64]
//   [262144,266240)   float  enorm[1024]

__device__ inline unsigned short bf16_rne(float f) {
    union { float fv; unsigned u; } a; a.fv = f;
    unsigned r = a.u + 0x7FFFu + ((a.u >> 16) & 1u);
    return (unsigned short)(r >> 16);
}
__device__ inline float bf16_to_f(unsigned short h) {
    union { unsigned u; float fv; } a; a.u = ((unsigned)h) << 16;
    return a.fv;
}
// packed (score, 1023-code) ordered compare via f64 max; near-ties are all
// rescored exactly, so tie direction here is irrelevant.
__device__ inline double dpack(float hi, unsigned lo) {
    return __hiloint2double(__float_as_int(hi), (int)lo);
}
__device__ inline float dhi(double d) { return __int_as_float(__double2hiint(d)); }
__device__ inline unsigned dlo(double d) { return (unsigned)__double2loint(d); }

__global__ __launch_bounds__(256) void vq_prep(const float* __restrict__ emb,
        unsigned short* __restrict__ epack, float* __restrict__ enorm,
        float* __restrict__ out) {
    const int k = blockIdx.x * 256 + threadIdx.x;   // grid 4
    if (k == 0) out[ZQ_ELEMS] = 0.f;
    const float4* e4 = (const float4*)(emb + k * 64);
    float s = 0.f;
#pragma unroll
    for (int j = 0; j < 16; ++j) {
        float4 v = e4[j];
        float vv[4] = {v.x, v.y, v.z, v.w};
        ushort4 hv, lv;
        unsigned short h[4], l[4];
#pragma unroll
        for (int t = 0; t < 4; ++t) {
            s = fmaf(vv[t], vv[t], s);
            h[t] = bf16_rne(vv[t]);
            l[t] = bf16_rne(vv[t] - bf16_to_f(h[t]));
        }
        hv.x = h[0]; hv.y = h[1]; hv.z = h[2]; hv.w = h[3];
        lv.x = l[0]; lv.y = l[1]; lv.z = l[2]; lv.w = l[3];
        *(ushort4*)(epack + k * 128 + j * 4)      = hv;
        *(ushort4*)(epack + k * 128 + 64 + j * 4) = lv;
    }
    enorm[k] = s;
}

// Mega: block = 64 px, 512 threads = 8 waves. Each wave holds 64 codes resident
// and does 2 passes (8w x 64c x 2 = 1024 codes). Then merge, rescore (from LDS
// z_e), gather, write z_q + loss -- all block-local. Grid 1024.
__global__ __launch_bounds__(512) void vq_mega(const float* __restrict__ z_e,
        const unsigned short* __restrict__ epack, const float* __restrict__ enorm,
        const float* __restrict__ emb, float* __restrict__ out) {
    const int tid  = threadIdx.x;
    const int lane = tid & 63;
    const int col  = lane & 15;
    const int g    = lane >> 4;
    const int wv   = __builtin_amdgcn_readfirstlane(tid >> 6);   // 0..7
    const int pblk = blockIdx.x * 64;

    __shared__ float zfp[64][65];                    // exact fp32 z_e copy
    __shared__ __align__(16) char ubuf[16640];       // afrag (MFMA) then zq (gather)
    unsigned short* afrag = (unsigned short*)ubuf;   // [64 px][hi64|lo64], swizzled
    float (*zq)[65] = (float (*)[65])ubuf;
    __shared__ double mrgB[8][64];
    __shared__ float  mrgS[8][64];
    __shared__ int    sidx[64];
    __shared__ unsigned long long smask;
    __shared__ float  sred[8];

    // ---- stage: 8 threads per px (one per wave), 8 dims each; fp32 + bf16 hi/lo
    {
        const int pg = pblk + lane;
        const float* zb = z_e + (pg >> 12) * 262144 + (pg & 4095);
        const int d0 = wv * 8;
        short8 H, L;
#pragma unroll
        for (int j = 0; j < 8; ++j) {
            const float v = zb[(d0 + j) * 4096];
            zfp[lane][d0 + j] = v;
            const unsigned short h = bf16_rne(v);
            H[j] = (short)h;
            L[j] = (short)bf16_rne(v - bf16_to_f(h));
        }
        const int sw = d0 ^ ((lane & 7) << 3);       // 16B-granular XOR swizzle
        *(short8*)&afrag[lane * 128 + sw]      = H;
        *(short8*)&afrag[lane * 128 + 64 + sw] = L;
    }
    __syncthreads();

    double Brun[4];
    float  Srun[4];
#pragma unroll
    for (int it = 0; it < 4; ++it) { Brun[it] = dpack(-INFINITY, 0u); Srun[it] = -INFINITY; }

    const f32x4 zero4 = {0.f, 0.f, 0.f, 0.f};
    const int g8 = g * 8;

#pragma unroll 1
    for (int grp = 0; grp < 2; ++grp) {
        const int cbase = grp * 512 + wv * 64;       // this wave's 64 codes this pass
        short8 ah[4][2], al[4][2];
        f32x4 enf[4];
#pragma unroll
        for (int t = 0; t < 4; ++t) {
            const int code = cbase + t * 16 + col;
            const short8* ph = (const short8*)(epack + code * 128) + g;
            ah[t][0] = ph[0]; ah[t][1] = ph[4];
            al[t][0] = ph[8]; al[t][1] = ph[12];
            const float4 e4 = *(const float4*)(enorm + cbase + t * 16 + g * 4);
            enf[t][0] = -0.5f * e4.x; enf[t][1] = -0.5f * e4.y;
            enf[t][2] = -0.5f * e4.z; enf[t][3] = -0.5f * e4.w;
        }
        const int K1 = 1023 - cbase - g * 4;

#pragma unroll
        for (int it = 0; it < 4; ++it) {
            const int lpx = it * 16 + col;           // this lane's pixel (local)
            const int sxp = (lpx & 7) << 3;
            const unsigned short* ap = &afrag[lpx * 128];
            // B fragment: lane k-group g holds dims g*8..+7 / 32+g*8..+7
            const short8 bh0 = *(const short8*)&ap[(g8     ) ^ sxp];
            const short8 bh1 = *(const short8*)&ap[(32 + g8) ^ sxp];
            const short8 bl0 = *(const short8*)&ap[64 + ((g8     ) ^ sxp)];
            const short8 bl1 = *(const short8*)&ap[64 + ((32 + g8) ^ sxp)];

            double B = Brun[it];
            float  S = Srun[it];
#pragma unroll
            for (int t = 0; t < 4; ++t) {
                f32x4 aA, aB;   // chunk0 / chunk1 independent 3-chains
                aA = __builtin_amdgcn_mfma_f32_16x16x32_bf16(ah[t][0], bh0, enf[t], 0, 0, 0);
                aB = __builtin_amdgcn_mfma_f32_16x16x32_bf16(ah[t][1], bh1, zero4, 0, 0, 0);
                aA = __builtin_amdgcn_mfma_f32_16x16x32_bf16(al[t][0], bh0, aA, 0, 0, 0);
                aB = __builtin_amdgcn_mfma_f32_16x16x32_bf16(al[t][1], bh1, aB, 0, 0, 0);
                aA = __builtin_amdgcn_mfma_f32_16x16x32_bf16(ah[t][0], bl0, aA, 0, 0, 0);
                aB = __builtin_amdgcn_mfma_f32_16x16x32_bf16(ah[t][1], bl1, aB, 0, 0, 0);
#pragma unroll
                for (int r = 0; r < 4; ++r) {
                    const float v = aA[r] + aB[r];   // score(code=cbase+t*16+g*4+r, px)
                    S = __builtin_amdgcn_fmed3f(dhi(B), S, v);
                    B = fmax(B, dpack(v, (unsigned)(K1 - t * 16 - r)));
                }
            }
            Brun[it] = B;
            Srun[it] = S;
        }
    }

    // ---- reduce over g (lane bits 4-5), stash per-wave results
#pragma unroll
    for (int it = 0; it < 4; ++it) {
        double B = Brun[it];
        float  S = Srun[it];
#pragma unroll
        for (int s = 16; s < 64; s <<= 1) {
            const double ob = __shfl_xor(B, s, 64);
            const float  o2 = __shfl_xor(S, s, 64);
            S = __builtin_amdgcn_fmed3f(dhi(B), dhi(ob), fmaxf(S, o2));
            B = fmax(B, ob);
        }
        if (g == 0) { mrgB[wv][it * 16 + col] = B; mrgS[wv][it * 16 + col] = S; }
    }
    __syncthreads();

    // ---- merge the 8 waves' results -> index + risky ballot (wave 0)
    if (tid < 64) {
        double B = mrgB[0][tid];
        float  S = mrgS[0][tid];
#pragma unroll
        for (int w = 1; w < 8; ++w) {
            const double ob = mrgB[w][tid];
            const float  o2 = mrgS[w][tid];
            S = __builtin_amdgcn_fmed3f(dhi(B), dhi(ob), fmaxf(S, o2));
            B = fmax(B, ob);
        }
        sidx[tid] = 1023 - (int)dlo(B);
        const unsigned long long m = __ballot(dhi(B) - S < EPS_HALF);
        if (tid == 0) smask = m;
    }
    __syncthreads();

    // ---- exact fp64 rescore of flagged px (z_e from LDS), round-robin over waves
    {
        unsigned long long m = smask;
        int item = 0;
        while (m) {
            const int i = __builtin_ctzll(m);
            m &= m - 1;
            if ((item & 7) == wv) {
                float f[64];
#pragma unroll
                for (int d = 0; d < 64; ++d) f[d] = zfp[i][d];
                double best = INFINITY; int bk = KC;
                for (int j = 0; j < 16; ++j) {
                    const int k = j * 64 + lane;
                    const float* e = emb + k * 64;
                    double a0 = 0.0, a1 = 0.0;
#pragma unroll
                    for (int d = 0; d < 64; d += 2) {
                        const double d0 = (double)f[d]     - (double)e[d];
                        const double d1 = (double)f[d + 1] - (double)e[d + 1];
                        a0 = fma(d0, d0, a0);
                        a1 = fma(d1, d1, a1);
                    }
                    const double acc = a0 + a1;
                    if (acc < best || (acc == best && k < bk)) { best = acc; bk = k; }
                }
                for (int off = 32; off; off >>= 1) {
                    const double ov = __shfl_down(best, off, 64);
                    const int    oi = __shfl_down(bk, off, 64);
                    if (ov < best || (ov == best && oi < bk)) { best = ov; bk = oi; }
                }
                if (lane == 0) sidx[i] = bk;
            }
            ++item;
        }
    }
    __syncthreads();

    // ---- write indices
    if (tid < 64) out[ZQ_ELEMS + 1 + pblk + tid] = (float)sidx[tid];

    // ---- gather: coalesced codebook-row reads into zq (reuses afrag LDS)
#pragma unroll
    for (int i = 0; i < 8; ++i) {
        const int p = wv * 8 + i;
        const int k = sidx[p];                       // LDS, wave-uniform broadcast
        zq[p][lane] = emb[k * 64 + lane];
    }
    __syncthreads();

    // ---- (B,D,H,W)-major float4 writes + fused loss (z from LDS zfp)
    const int p4 = (tid & 15) * 4;
    const int dd = tid >> 4;                          // 0..31
    const int batch = pblk >> 12;
    const int hw0   = pblk & 4095;
    float* ob = out + batch * 262144 + hw0;
    float ss = 0.f;
#pragma unroll
    for (int h = 0; h < 2; ++h) {
        const int d = dd + h * 32;
        float4 q;
        q.x = zq[p4 + 0][d]; q.y = zq[p4 + 1][d];
        q.z = zq[p4 + 2][d]; q.w = zq[p4 + 3][d];
        const float z0 = zfp[p4 + 0][d], z1 = zfp[p4 + 1][d];
        const float z2 = zfp[p4 + 2][d], z3 = zfp[p4 + 3][d];
        *(float4*)(ob + d * 4096 + p4) = q;
        const float e0 = q.x - z0, e1 = q.y - z1, e2 = q.z - z2, e3 = q.w - z3;
        ss += e0 * e0 + e1 * e1 + e2 * e2 + e3 * e3;
    }
    for (int off = 32; off; off >>= 1) ss += __shfl_down(ss, off, 64);
    if (lane == 0) sred[wv] = ss;
    __syncthreads();
    if (tid == 0) {
        float tot = 0.f;
#pragma unroll
        for (int w = 0; w < 8; ++w) tot += sred[w];
        atomicAdd(out + ZQ_ELEMS, tot * (1.25f / (float)ZQ_ELEMS));
    }
}

extern "C" void kernel_launch(void* const* d_in, const int* in_sizes, int n_in,
                              void* d_out, int out_size, void* d_ws, size_t ws_size,
                              hipStream_t stream) {
    const float* z_e = (const float*)d_in[0];
    const float* emb = (const float*)d_in[1];
    float* out = (float*)d_out;
    char* ws = (char*)d_ws;
    unsigned short* epack = (unsigned short*)ws;
    float* enorm = (float*)(ws + 262144);

    vq_prep<<<4, 256, 0, stream>>>(emb, epack, enorm, out);
    vq_mega<<<1024, 512, 0, stream>>>(z_e, epack, enorm, emb, out);
}